// Round 5
// baseline (570.538 us; speedup 1.0000x reference)
//
#include <hip/hip_runtime.h>
#include <hip/hip_cooperative_groups.h>

namespace cg = cooperative_groups;

// NNConv x3 + MLP head. W_e = a0*A0 + a1*A1 + B (affine in 2 edge attrs) =>
// aggr_n = (sum a0*x_src)@A0 + (sum a1*x_src)@A1 + (sum x_src)@B.
// Plan A: ONE cooperative kernel (512 blocks @ 2/CU), 8 grid.sync phases.
// Plan B (if coop launch fails): round-3 multi-kernel path (known good).

struct Params {
    const float* x; const int* src; const int* dst; const float* ea;
    const float* nn1W; const float* nn1b; const float* root1; const float* b1;
    const float* nn2W; const float* nn2b; const float* root2; const float* b2;
    const float* nn3W; const float* nn3b; const float* root3; const float* b3;
    const float* fc1W; const float* fc1b; const float* fc2W; const float* fc2b;
    int* cnt; int* off; int* cur; int* esc; int* bsum; int* boff;
    int* s_src; float* s_a0; float* s_a1; float* h1; float* h2; float* out;
    int N; int E;
};

__global__ __launch_bounds__(256, 2) void fused_kernel(Params P) {
    cg::grid_group grid = cg::this_grid();
    __shared__ float lA0[1024], lA1[1024], lB[1024], lR[1024];
    __shared__ float ls[8 * 128];
    __shared__ int ish[256];

    const int t = threadIdx.x;
    const int g = t >> 5, lane = t & 31;
    const int gid = blockIdx.x * 256 + t;
    const int GT = gridDim.x * 256;
    const int NBk = (P.N + 255) >> 8;  // 79 scan chunks (<=256)

    // P0: zero cnt
    for (int i = gid; i < P.N; i += GT) P.cnt[i] = 0;
    grid.sync();

    // P1: histogram of dst
    for (int e = gid; e < P.E; e += GT) atomicAdd(&P.cnt[P.dst[e]], 1);
    grid.sync();

    // P2a: per-chunk local scan -> esc (exclusive within chunk), bsum
    for (int b = blockIdx.x; b < NBk; b += gridDim.x) {
        int i = b * 256 + t;
        int v = (i < P.N) ? P.cnt[i] : 0;
        ish[t] = v;
        __syncthreads();
        for (int d = 1; d < 256; d <<= 1) {
            int u = (t >= d) ? ish[t - d] : 0;
            __syncthreads();
            ish[t] += u;
            __syncthreads();
        }
        if (i < P.N) P.esc[i] = ish[t] - v;
        if (t == 255) P.bsum[b] = ish[255];
        __syncthreads();
    }
    grid.sync();

    // P2b: block 0 scans chunk sums -> boff, off[N]=total
    if (blockIdx.x == 0) {
        int v = (t < NBk) ? P.bsum[t] : 0;
        ish[t] = v;
        __syncthreads();
        for (int d = 1; d < 256; d <<= 1) {
            int u = (t >= d) ? ish[t - d] : 0;
            __syncthreads();
            ish[t] += u;
            __syncthreads();
        }
        if (t < NBk) P.boff[t] = ish[t] - v;
        if (t == 255) P.off[P.N] = ish[255];
    }
    grid.sync();

    // P2c: off = cur = boff[chunk] + esc
    for (int i = gid; i < P.N; i += GT) {
        int o = P.boff[i >> 8] + P.esc[i];
        P.off[i] = o;
        P.cur[i] = o;
    }
    grid.sync();

    // P3: scatter edges into dst-sorted CSR order
    for (int e = gid; e < P.E; e += GT) {
        int d = P.dst[e];
        int p = atomicAdd(&P.cur[d], 1);
        float2 a = ((const float2*)P.ea)[e];
        P.s_src[p] = P.src[e];
        P.s_a0[p] = a.x;
        P.s_a1[p] = a.y;
    }
    grid.sync();

    // P4: conv1 (in=2, out=32). 8 nodes/block, 32 lanes/node (lane = out feature).
    for (int n = blockIdx.x * 8 + g; n < P.N; n += gridDim.x * 8) {
        int beg = P.off[n], end = P.off[n + 1];
        float p0 = 0, p1 = 0, q0 = 0, q1 = 0, r0 = 0, r1 = 0;
        for (int p = beg; p < end; p++) {
            float a0 = P.s_a0[p], a1 = P.s_a1[p];
            float2 xv = ((const float2*)P.x)[P.s_src[p]];
            p0 = fmaf(a0, xv.x, p0);
            p1 = fmaf(a0, xv.y, p1);
            q0 = fmaf(a1, xv.x, q0);
            q1 = fmaf(a1, xv.y, q1);
            r0 += xv.x;
            r1 += xv.y;
        }
        float acc = P.b1[lane];
        acc = fmaf(p0, P.nn1W[lane * 2], acc);
        acc = fmaf(p1, P.nn1W[(32 + lane) * 2], acc);
        acc = fmaf(q0, P.nn1W[lane * 2 + 1], acc);
        acc = fmaf(q1, P.nn1W[(32 + lane) * 2 + 1], acc);
        acc = fmaf(r0, P.nn1b[lane], acc);
        acc = fmaf(r1, P.nn1b[32 + lane], acc);
        float2 xn = ((const float2*)P.x)[n];
        acc = fmaf(xn.x, P.root1[lane], acc);
        acc = fmaf(xn.y, P.root1[32 + lane], acc);
        P.h1[n * 32 + lane] = fmaxf(acc, 0.f);
    }
    grid.sync();

    // P5: conv2 (32->32), weights staged in LDS.
    for (int k = t; k < 1024; k += 256) {
        float2 w = ((const float2*)P.nn2W)[k];
        lA0[k] = w.x;
        lA1[k] = w.y;
        lB[k] = P.nn2b[k];
        lR[k] = P.root2[k];
    }
    __syncthreads();
    {
        float* myls = &ls[g * 128];
        for (int n = blockIdx.x * 8 + g; n < P.N; n += gridDim.x * 8) {
            int beg = P.off[n], end = P.off[n + 1];
            float s0 = 0, s1 = 0, s2 = 0;
            for (int p = beg; p < end; p++) {
                float a0 = P.s_a0[p], a1 = P.s_a1[p];
                float xv = P.h1[P.s_src[p] * 32 + lane];
                s0 = fmaf(a0, xv, s0);
                s1 = fmaf(a1, xv, s1);
                s2 += xv;
            }
            // half-wave-private LDS region; same-wave LDS ops are in order
            myls[lane] = s0;
            myls[32 + lane] = s1;
            myls[64 + lane] = s2;
            myls[96 + lane] = P.h1[n * 32 + lane];
            float acc = P.b2[lane];
#pragma unroll
            for (int i = 0; i < 32; i++) {
                acc = fmaf(myls[i], lA0[i * 32 + lane], acc);
                acc = fmaf(myls[32 + i], lA1[i * 32 + lane], acc);
                acc = fmaf(myls[64 + i], lB[i * 32 + lane], acc);
                acc = fmaf(myls[96 + i], lR[i * 32 + lane], acc);
            }
            P.h2[n * 32 + lane] = fmaxf(acc, 0.f);
        }
    }
    grid.sync();

    // P6: conv3 (32->32) + fc1(relu) + fc2 -> out[N].
    for (int k = t; k < 1024; k += 256) {
        float2 w = ((const float2*)P.nn3W)[k];
        lA0[k] = w.x;
        lA1[k] = w.y;
        lB[k] = P.nn3b[k];
        lR[k] = P.root3[k];
    }
    __syncthreads();
    {
        float* myls = &ls[g * 128];
        for (int n = blockIdx.x * 8 + g; n < P.N; n += gridDim.x * 8) {
            int beg = P.off[n], end = P.off[n + 1];
            float s0 = 0, s1 = 0, s2 = 0;
            for (int p = beg; p < end; p++) {
                float a0 = P.s_a0[p], a1 = P.s_a1[p];
                float xv = P.h2[P.s_src[p] * 32 + lane];
                s0 = fmaf(a0, xv, s0);
                s1 = fmaf(a1, xv, s1);
                s2 += xv;
            }
            myls[lane] = s0;
            myls[32 + lane] = s1;
            myls[64 + lane] = s2;
            myls[96 + lane] = P.h2[n * 32 + lane];
            float acc = P.b3[lane];
#pragma unroll
            for (int i = 0; i < 32; i++) {
                acc = fmaf(myls[i], lA0[i * 32 + lane], acc);
                acc = fmaf(myls[32 + i], lA1[i * 32 + lane], acc);
                acc = fmaf(myls[64 + i], lB[i * 32 + lane], acc);
                acc = fmaf(myls[96 + i], lR[i * 32 + lane], acc);
            }
            acc = fmaxf(acc, 0.f);  // h3
            myls[lane] = acc;
            float z = P.fc1b[lane];
#pragma unroll
            for (int o = 0; o < 32; o++) z = fmaf(myls[o], P.fc1W[lane * 32 + o], z);
            z = fmaxf(z, 0.f);
            float v = z * P.fc2W[lane];
#pragma unroll
            for (int m = 1; m < 32; m <<= 1) v += __shfl_xor(v, m);
            if (lane == 0) P.out[n] = v + P.fc2b[0];
        }
    }
}

// ---------------- Plan B: round-3 multi-kernel path (known good) -------------

__global__ void hist_kernel(const int* __restrict__ dst, int* __restrict__ cnt, int E) {
    int e = blockIdx.x * blockDim.x + threadIdx.x;
    if (e < E) atomicAdd(&cnt[dst[e]], 1);
}

__global__ __launch_bounds__(256) void scanA_kernel(const int* __restrict__ cnt,
                                                    int* __restrict__ esc,
                                                    int* __restrict__ bsum, int N) {
    __shared__ int sh[256];
    int t = threadIdx.x;
    int i = blockIdx.x * 256 + t;
    int v = (i < N) ? cnt[i] : 0;
    sh[t] = v;
    __syncthreads();
    for (int d = 1; d < 256; d <<= 1) {
        int u = (t >= d) ? sh[t - d] : 0;
        __syncthreads();
        sh[t] += u;
        __syncthreads();
    }
    if (i < N) esc[i] = sh[t] - v;
    if (t == 255) bsum[blockIdx.x] = sh[255];
}

__global__ __launch_bounds__(128) void scanB_kernel(const int* __restrict__ bsum,
                                                    int* __restrict__ boff,
                                                    int* __restrict__ off, int NB, int N) {
    __shared__ int sh[128];
    int t = threadIdx.x;
    int v = (t < NB) ? bsum[t] : 0;
    sh[t] = v;
    __syncthreads();
    for (int d = 1; d < 128; d <<= 1) {
        int u = (t >= d) ? sh[t - d] : 0;
        __syncthreads();
        sh[t] += u;
        __syncthreads();
    }
    if (t < NB) boff[t] = sh[t] - v;
    if (t == 127) off[N] = sh[127];
}

__global__ __launch_bounds__(256) void scanC_kernel(const int* __restrict__ esc,
                                                    const int* __restrict__ boff,
                                                    int* __restrict__ off,
                                                    int* __restrict__ cur, int N) {
    int i = blockIdx.x * 256 + threadIdx.x;
    if (i < N) {
        int o = boff[blockIdx.x] + esc[i];
        off[i] = o;
        cur[i] = o;
    }
}

__global__ void scatter_kernel(const int* __restrict__ src, const int* __restrict__ dst,
                               const float* __restrict__ ea, int* __restrict__ cur,
                               int* __restrict__ s_src, float* __restrict__ s_a0,
                               float* __restrict__ s_a1, int E) {
    int e = blockIdx.x * blockDim.x + threadIdx.x;
    if (e < E) {
        int d = dst[e];
        int p = atomicAdd(&cur[d], 1);
        s_src[p] = src[e];
        s_a0[p] = ea[2 * e];
        s_a1[p] = ea[2 * e + 1];
    }
}

__global__ __launch_bounds__(256) void conv1_kernel(
    const float* __restrict__ x, const int* __restrict__ off,
    const int* __restrict__ s_src, const float* __restrict__ s_a0,
    const float* __restrict__ s_a1, const float* __restrict__ nnW,
    const float* __restrict__ nnb, const float* __restrict__ root,
    const float* __restrict__ bias, float* __restrict__ hout, int N) {
    int tid = threadIdx.x;
    int g = tid >> 5, lane = tid & 31;
    int n = blockIdx.x * 8 + g;
    if (n >= N) return;
    int beg = off[n], end = off[n + 1];
    float p0 = 0, p1 = 0, q0 = 0, q1 = 0, r0 = 0, r1 = 0;
    for (int p = beg; p < end; p++) {
        float a0 = s_a0[p], a1 = s_a1[p];
        int s = s_src[p];
        float x0 = x[2 * s], x1 = x[2 * s + 1];
        p0 = fmaf(a0, x0, p0);
        p1 = fmaf(a0, x1, p1);
        q0 = fmaf(a1, x0, q0);
        q1 = fmaf(a1, x1, q1);
        r0 += x0;
        r1 += x1;
    }
    float acc = bias[lane];
    acc = fmaf(p0, nnW[lane * 2], acc);
    acc = fmaf(p1, nnW[(32 + lane) * 2], acc);
    acc = fmaf(q0, nnW[lane * 2 + 1], acc);
    acc = fmaf(q1, nnW[(32 + lane) * 2 + 1], acc);
    acc = fmaf(r0, nnb[lane], acc);
    acc = fmaf(r1, nnb[32 + lane], acc);
    acc = fmaf(x[2 * n], root[lane], acc);
    acc = fmaf(x[2 * n + 1], root[32 + lane], acc);
    hout[n * 32 + lane] = fmaxf(acc, 0.f);
}

__global__ __launch_bounds__(256) void conv32_kernel(
    const float* __restrict__ hin, const int* __restrict__ off,
    const int* __restrict__ s_src, const float* __restrict__ s_a0,
    const float* __restrict__ s_a1, const float* __restrict__ nnW,
    const float* __restrict__ nnb, const float* __restrict__ root,
    const float* __restrict__ bias, float* __restrict__ hout,
    const float* __restrict__ fc1W, const float* __restrict__ fc1b,
    const float* __restrict__ fc2W, const float* __restrict__ fc2b,
    float* __restrict__ out, int N) {
    __shared__ float lA0[1024], lA1[1024], lB[1024], lR[1024];
    __shared__ float ls[8 * 128];
    __shared__ float lsH[256];
    int tid = threadIdx.x;
    for (int k = tid; k < 1024; k += 256) {
        lA0[k] = nnW[2 * k];
        lA1[k] = nnW[2 * k + 1];
        lB[k] = nnb[k];
        lR[k] = root[k];
    }
    __syncthreads();
    int g = tid >> 5, lane = tid & 31;
    int n = blockIdx.x * 8 + g;
    float s0 = 0, s1 = 0, s2 = 0, s3 = 0;
    if (n < N) {
        int beg = off[n], end = off[n + 1];
        for (int p = beg; p < end; p++) {
            float a0 = s_a0[p], a1 = s_a1[p];
            float xv = hin[s_src[p] * 32 + lane];
            s0 = fmaf(a0, xv, s0);
            s1 = fmaf(a1, xv, s1);
            s2 += xv;
        }
        s3 = hin[n * 32 + lane];
    }
    float* myls = &ls[g * 128];
    myls[lane] = s0;
    myls[32 + lane] = s1;
    myls[64 + lane] = s2;
    myls[96 + lane] = s3;
    __syncthreads();
    float acc = bias[lane];
#pragma unroll
    for (int i = 0; i < 32; i++) {
        acc = fmaf(myls[i], lA0[i * 32 + lane], acc);
        acc = fmaf(myls[32 + i], lA1[i * 32 + lane], acc);
        acc = fmaf(myls[64 + i], lB[i * 32 + lane], acc);
        acc = fmaf(myls[96 + i], lR[i * 32 + lane], acc);
    }
    acc = fmaxf(acc, 0.f);
    if (out == nullptr) {
        if (n < N) hout[n * 32 + lane] = acc;
    } else {
        lsH[g * 32 + lane] = acc;
        __syncthreads();
        float z = fc1b[lane];
#pragma unroll
        for (int o = 0; o < 32; o++) z = fmaf(lsH[g * 32 + o], fc1W[lane * 32 + o], z);
        z = fmaxf(z, 0.f);
        float v = z * fc2W[lane];
#pragma unroll
        for (int m = 1; m < 32; m <<= 1) v += __shfl_xor(v, m);
        if (lane == 0 && n < N) out[n] = v + fc2b[0];
    }
}

static inline size_t align256(size_t x) { return (x + 255) & ~(size_t)255; }

extern "C" void kernel_launch(void* const* d_in, const int* in_sizes, int n_in,
                              void* d_out, int out_size, void* d_ws, size_t ws_size,
                              hipStream_t stream) {
    const int N = in_sizes[0] / 2;   // 20000
    const int E = in_sizes[2] / 2;   // 150000
    const int NB = (N + 255) / 256;

    Params P;
    P.x = (const float*)d_in[0];
    const int* ei = (const int*)d_in[1];
    P.src = ei;
    P.dst = ei + E;
    P.ea = (const float*)d_in[2];
    P.nn1W = (const float*)d_in[3];
    P.nn1b = (const float*)d_in[4];
    P.root1 = (const float*)d_in[5];
    P.b1 = (const float*)d_in[6];
    P.nn2W = (const float*)d_in[7];
    P.nn2b = (const float*)d_in[8];
    P.root2 = (const float*)d_in[9];
    P.b2 = (const float*)d_in[10];
    P.nn3W = (const float*)d_in[11];
    P.nn3b = (const float*)d_in[12];
    P.root3 = (const float*)d_in[13];
    P.b3 = (const float*)d_in[14];
    P.fc1W = (const float*)d_in[15];
    P.fc1b = (const float*)d_in[16];
    P.fc2W = (const float*)d_in[17];
    P.fc2b = (const float*)d_in[18];

    char* w = (char*)d_ws;
    P.cnt = (int*)w;     w += align256((size_t)N * 4);
    P.off = (int*)w;     w += align256((size_t)(N + 1) * 4);
    P.cur = (int*)w;     w += align256((size_t)N * 4);
    P.esc = (int*)w;     w += align256((size_t)N * 4);
    P.bsum = (int*)w;    w += align256((size_t)NB * 4);
    P.boff = (int*)w;    w += align256((size_t)NB * 4);
    P.s_src = (int*)w;   w += align256((size_t)E * 4);
    P.s_a0 = (float*)w;  w += align256((size_t)E * 4);
    P.s_a1 = (float*)w;  w += align256((size_t)E * 4);
    P.h1 = (float*)w;    w += align256((size_t)N * 32 * 4);
    P.h2 = (float*)w;    w += align256((size_t)N * 32 * 4);
    P.out = (float*)d_out;
    P.N = N;
    P.E = E;

    void* args[] = {&P};
    hipError_t err = hipLaunchCooperativeKernel((const void*)fused_kernel, dim3(512),
                                                dim3(256), args, 0, stream);
    if (err == hipSuccess) return;

    // Plan B: multi-kernel fallback (identical math).
    hipMemsetAsync(P.cnt, 0, (size_t)N * 4, stream);
    int eb = (E + 255) / 256;
    hist_kernel<<<eb, 256, 0, stream>>>(P.dst, P.cnt, E);
    scanA_kernel<<<NB, 256, 0, stream>>>(P.cnt, P.esc, P.bsum, N);
    scanB_kernel<<<1, 128, 0, stream>>>(P.bsum, P.boff, P.off, NB, N);
    scanC_kernel<<<NB, 256, 0, stream>>>(P.esc, P.boff, P.off, P.cur, N);
    scatter_kernel<<<eb, 256, 0, stream>>>(P.src, P.dst, P.ea, P.cur,
                                           P.s_src, P.s_a0, P.s_a1, E);
    int nb = (N + 7) / 8;
    conv1_kernel<<<nb, 256, 0, stream>>>(P.x, P.off, P.s_src, P.s_a0, P.s_a1,
                                         P.nn1W, P.nn1b, P.root1, P.b1, P.h1, N);
    conv32_kernel<<<nb, 256, 0, stream>>>(P.h1, P.off, P.s_src, P.s_a0, P.s_a1,
                                          P.nn2W, P.nn2b, P.root2, P.b2, P.h2,
                                          nullptr, nullptr, nullptr, nullptr,
                                          nullptr, N);
    conv32_kernel<<<nb, 256, 0, stream>>>(P.h2, P.off, P.s_src, P.s_a0, P.s_a1,
                                          P.nn3W, P.nn3b, P.root3, P.b3, nullptr,
                                          P.fc1W, P.fc1b, P.fc2W, P.fc2b,
                                          (float*)d_out, N);
}

// Round 6
// 336.805 us; speedup vs baseline: 1.6940x; 1.6940x over previous
//
#include <hip/hip_runtime.h>

// NNConv x3 + MLP head. W_e = a0*A0 + a1*A1 + B (affine in 2 edge attrs) =>
// aggr_n = (sum a0*x_src)@A0 + (sum a1*x_src)@A1 + (sum x_src)@B.
// ONE cooperative kernel with CUSTOM hierarchical grid barriers (ROCm grid.sync
// measured ~59us/sync on MI355X; hipMemsetAsync measured ~41us in-graph).
// Phases: hist |B0| lookback-scan |B1| scatter |B2| conv1 |B3| conv2 |B4| conv3+head.
// Zero-init (cnt/agg/bars) via a tiny zero_kernel, NOT hipMemsetAsync.

#define BAR_SLOT 256  // ints between barrier counters (1KB apart, spread L2 channels)
#define NBARS 5

struct Params {
    const float* x; const int* src; const int* dst; const float* ea;
    const float* nn1W; const float* nn1b; const float* root1; const float* b1;
    const float* nn2W; const float* nn2b; const float* root2; const float* b2;
    const float* nn3W; const float* nn3b; const float* root3; const float* b3;
    const float* fc1W; const float* fc1b; const float* fc2W; const float* fc2b;
    int* cnt; int* agg; int* bars; int* off; int* cur;
    int* esc; int* bsum; int* boff;      // Plan B only
    int4* edges; float* h1; float* h2; float* out;
    int N; int E;
};

__global__ __launch_bounds__(256) void zero_kernel(int* p, int n) {
    int i = blockIdx.x * 256 + threadIdx.x;
    int gt = gridDim.x * 256;
    for (; i < n; i += gt) p[i] = 0;
}

// Hierarchical grid barrier: 8 sub-counters (by blockIdx&7) -> 1 root.
// Counters pre-zeroed; one instance per barrier id per call.
__device__ __forceinline__ void gbar(int* bars, int bid, int nb) {
    __syncthreads();
    if (threadIdx.x == 0) {
        int k = blockIdx.x & 7;
        int* grp = bars + (bid * 9 + k) * BAR_SLOT;
        int* root = bars + (bid * 9 + 8) * BAR_SLOT;
        int gsz = (nb >> 3) + ((k < (nb & 7)) ? 1 : 0);
        int old = __hip_atomic_fetch_add(grp, 1, __ATOMIC_ACQ_REL, __HIP_MEMORY_SCOPE_AGENT);
        if (old == gsz - 1)
            __hip_atomic_fetch_add(root, 1, __ATOMIC_ACQ_REL, __HIP_MEMORY_SCOPE_AGENT);
        while (__hip_atomic_load(root, __ATOMIC_ACQUIRE, __HIP_MEMORY_SCOPE_AGENT) < 8)
            __builtin_amdgcn_s_sleep(1);
    }
    __syncthreads();
}

__global__ __launch_bounds__(256, 2) void fused_kernel(Params P) {
    __shared__ float lA0[1024], lA1[1024], lB[1024], lR[1024];
    __shared__ float ls[8 * 128];
    __shared__ int ish[256];

    const int t = threadIdx.x;
    const int g = t >> 5, lane = t & 31;
    const int nb = gridDim.x;
    const int gid = blockIdx.x * 256 + t;
    const int GT = nb * 256;
    const int NBk = (P.N + 255) >> 8;  // 79 scan chunks (<= 256)

    // P1: histogram of dst (cnt pre-zeroed by zero_kernel)
    for (int e = gid; e < P.E; e += GT) atomicAdd(&P.cnt[P.dst[e]], 1);
    gbar(P.bars, 0, nb);

    // P2: single-pass scan with decoupled lookback; block b handles chunk b.
    if (blockIdx.x < NBk) {
        int b = blockIdx.x;
        int i = b * 256 + t;
        int v = (i < P.N) ? P.cnt[i] : 0;
        ish[t] = v;
        __syncthreads();
        for (int d = 1; d < 256; d <<= 1) {
            int u = (t >= d) ? ish[t - d] : 0;
            __syncthreads();
            ish[t] += u;
            __syncthreads();
        }
        int e = ish[t] - v;        // exclusive within chunk
        int total = ish[255];
        __syncthreads();           // done reading ish; safe to reuse
        if (t == 0)
            __hip_atomic_store(&P.agg[b], total + 1, __ATOMIC_RELEASE,
                               __HIP_MEMORY_SCOPE_AGENT);
        int a = 0;
        if (t < b) {  // t < b <= 78: thread t fetches chunk t's aggregate
            int xv;
            while ((xv = __hip_atomic_load(&P.agg[t], __ATOMIC_ACQUIRE,
                                           __HIP_MEMORY_SCOPE_AGENT)) == 0)
                __builtin_amdgcn_s_sleep(1);
            a = xv - 1;
        }
        ish[t] = a;
        __syncthreads();
        for (int d = 128; d > 0; d >>= 1) {
            if (t < d) ish[t] += ish[t + d];
            __syncthreads();
        }
        int o = ish[0] + e;
        if (i < P.N) {
            P.off[i] = o;
            P.cur[i] = o;
            if (i == P.N - 1) P.off[P.N] = o + v;
        }
    }
    gbar(P.bars, 1, nb);

    // P3: scatter edges into dst-CSR order; payload packed in one int4.
    for (int e = gid; e < P.E; e += GT) {
        int d = P.dst[e];
        int p = atomicAdd(&P.cur[d], 1);
        float2 a = ((const float2*)P.ea)[e];
        int s = P.src[e];
        int4 ed;
        ed.x = s;
        ed.y = __float_as_int(a.x);
        ed.z = __float_as_int(a.y);
        ed.w = s * 32;
        P.edges[p] = ed;
    }
    gbar(P.bars, 2, nb);

    // P4: conv1 (in=2, out=32). 8 nodes/block, 32 lanes/node (lane = out feat).
    for (int n = blockIdx.x * 8 + g; n < P.N; n += nb * 8) {
        int beg = P.off[n], end = P.off[n + 1];
        float p0 = 0, p1 = 0, q0 = 0, q1 = 0, r0 = 0, r1 = 0;
        for (int p = beg; p < end; p++) {
            int4 ed = P.edges[p];
            float a0 = __int_as_float(ed.y), a1 = __int_as_float(ed.z);
            float2 xv = ((const float2*)P.x)[ed.x];
            p0 = fmaf(a0, xv.x, p0);
            p1 = fmaf(a0, xv.y, p1);
            q0 = fmaf(a1, xv.x, q0);
            q1 = fmaf(a1, xv.y, q1);
            r0 += xv.x;
            r1 += xv.y;
        }
        float acc = P.b1[lane];
        acc = fmaf(p0, P.nn1W[lane * 2], acc);
        acc = fmaf(p1, P.nn1W[(32 + lane) * 2], acc);
        acc = fmaf(q0, P.nn1W[lane * 2 + 1], acc);
        acc = fmaf(q1, P.nn1W[(32 + lane) * 2 + 1], acc);
        acc = fmaf(r0, P.nn1b[lane], acc);
        acc = fmaf(r1, P.nn1b[32 + lane], acc);
        float2 xn = ((const float2*)P.x)[n];
        acc = fmaf(xn.x, P.root1[lane], acc);
        acc = fmaf(xn.y, P.root1[32 + lane], acc);
        P.h1[n * 32 + lane] = fmaxf(acc, 0.f);
    }
    gbar(P.bars, 3, nb);

    // P5: conv2 (32->32), weights staged in LDS.
    for (int k = t; k < 1024; k += 256) {
        float2 w = ((const float2*)P.nn2W)[k];
        lA0[k] = w.x;
        lA1[k] = w.y;
        lB[k] = P.nn2b[k];
        lR[k] = P.root2[k];
    }
    __syncthreads();
    {
        float* myls = &ls[g * 128];
        for (int n = blockIdx.x * 8 + g; n < P.N; n += nb * 8) {
            int beg = P.off[n], end = P.off[n + 1];
            float s0 = 0, s1 = 0, s2 = 0;
            for (int p = beg; p < end; p++) {
                int4 ed = P.edges[p];
                float a0 = __int_as_float(ed.y), a1 = __int_as_float(ed.z);
                float xv = P.h1[ed.w + lane];
                s0 = fmaf(a0, xv, s0);
                s1 = fmaf(a1, xv, s1);
                s2 += xv;
            }
            // half-wave-private region; same-wave LDS ops are ordered
            myls[lane] = s0;
            myls[32 + lane] = s1;
            myls[64 + lane] = s2;
            myls[96 + lane] = P.h1[n * 32 + lane];
            float acc = P.b2[lane];
#pragma unroll
            for (int i = 0; i < 32; i++) {
                acc = fmaf(myls[i], lA0[i * 32 + lane], acc);
                acc = fmaf(myls[32 + i], lA1[i * 32 + lane], acc);
                acc = fmaf(myls[64 + i], lB[i * 32 + lane], acc);
                acc = fmaf(myls[96 + i], lR[i * 32 + lane], acc);
            }
            P.h2[n * 32 + lane] = fmaxf(acc, 0.f);
        }
    }
    gbar(P.bars, 4, nb);

    // P6: conv3 (32->32) + fc1(relu) + fc2 -> out[N].
    for (int k = t; k < 1024; k += 256) {
        float2 w = ((const float2*)P.nn3W)[k];
        lA0[k] = w.x;
        lA1[k] = w.y;
        lB[k] = P.nn3b[k];
        lR[k] = P.root3[k];
    }
    __syncthreads();
    {
        float* myls = &ls[g * 128];
        for (int n = blockIdx.x * 8 + g; n < P.N; n += nb * 8) {
            int beg = P.off[n], end = P.off[n + 1];
            float s0 = 0, s1 = 0, s2 = 0;
            for (int p = beg; p < end; p++) {
                int4 ed = P.edges[p];
                float a0 = __int_as_float(ed.y), a1 = __int_as_float(ed.z);
                float xv = P.h2[ed.w + lane];
                s0 = fmaf(a0, xv, s0);
                s1 = fmaf(a1, xv, s1);
                s2 += xv;
            }
            myls[lane] = s0;
            myls[32 + lane] = s1;
            myls[64 + lane] = s2;
            myls[96 + lane] = P.h2[n * 32 + lane];
            float acc = P.b3[lane];
#pragma unroll
            for (int i = 0; i < 32; i++) {
                acc = fmaf(myls[i], lA0[i * 32 + lane], acc);
                acc = fmaf(myls[32 + i], lA1[i * 32 + lane], acc);
                acc = fmaf(myls[64 + i], lB[i * 32 + lane], acc);
                acc = fmaf(myls[96 + i], lR[i * 32 + lane], acc);
            }
            acc = fmaxf(acc, 0.f);  // h3
            myls[lane] = acc;
            float z = P.fc1b[lane];
#pragma unroll
            for (int o = 0; o < 32; o++) z = fmaf(myls[o], P.fc1W[lane * 32 + o], z);
            z = fmaxf(z, 0.f);
            float v = z * P.fc2W[lane];
#pragma unroll
            for (int m = 1; m < 32; m <<= 1) v += __shfl_xor(v, m);
            if (lane == 0) P.out[n] = v + P.fc2b[0];
        }
    }
}

// ---------------- Plan B: multi-kernel fallback (known good) ----------------

__global__ void hist_kernel(const int* __restrict__ dst, int* __restrict__ cnt, int E) {
    int e = blockIdx.x * blockDim.x + threadIdx.x;
    if (e < E) atomicAdd(&cnt[dst[e]], 1);
}

__global__ __launch_bounds__(256) void scanA_kernel(const int* __restrict__ cnt,
                                                    int* __restrict__ esc,
                                                    int* __restrict__ bsum, int N) {
    __shared__ int sh[256];
    int t = threadIdx.x;
    int i = blockIdx.x * 256 + t;
    int v = (i < N) ? cnt[i] : 0;
    sh[t] = v;
    __syncthreads();
    for (int d = 1; d < 256; d <<= 1) {
        int u = (t >= d) ? sh[t - d] : 0;
        __syncthreads();
        sh[t] += u;
        __syncthreads();
    }
    if (i < N) esc[i] = sh[t] - v;
    if (t == 255) bsum[blockIdx.x] = sh[255];
}

__global__ __launch_bounds__(128) void scanB_kernel(const int* __restrict__ bsum,
                                                    int* __restrict__ boff,
                                                    int* __restrict__ off, int NB, int N) {
    __shared__ int sh[128];
    int t = threadIdx.x;
    int v = (t < NB) ? bsum[t] : 0;
    sh[t] = v;
    __syncthreads();
    for (int d = 1; d < 128; d <<= 1) {
        int u = (t >= d) ? sh[t - d] : 0;
        __syncthreads();
        sh[t] += u;
        __syncthreads();
    }
    if (t < NB) boff[t] = sh[t] - v;
    if (t == 127) off[N] = sh[127];
}

__global__ __launch_bounds__(256) void scanC_kernel(const int* __restrict__ esc,
                                                    const int* __restrict__ boff,
                                                    int* __restrict__ off,
                                                    int* __restrict__ cur, int N) {
    int i = blockIdx.x * 256 + threadIdx.x;
    if (i < N) {
        int o = boff[blockIdx.x] + esc[i];
        off[i] = o;
        cur[i] = o;
    }
}

__global__ void scatter_kernel(const int* __restrict__ src, const int* __restrict__ dst,
                               const float* __restrict__ ea, int* __restrict__ cur,
                               int4* __restrict__ edges, int E) {
    int e = blockIdx.x * blockDim.x + threadIdx.x;
    if (e < E) {
        int d = dst[e];
        int p = atomicAdd(&cur[d], 1);
        float2 a = ((const float2*)ea)[e];
        int s = src[e];
        int4 ed;
        ed.x = s;
        ed.y = __float_as_int(a.x);
        ed.z = __float_as_int(a.y);
        ed.w = s * 32;
        edges[p] = ed;
    }
}

__global__ __launch_bounds__(256) void conv1_kernel(
    const float* __restrict__ x, const int* __restrict__ off,
    const int4* __restrict__ edges, const float* __restrict__ nnW,
    const float* __restrict__ nnb, const float* __restrict__ root,
    const float* __restrict__ bias, float* __restrict__ hout, int N) {
    int tid = threadIdx.x;
    int g = tid >> 5, lane = tid & 31;
    int n = blockIdx.x * 8 + g;
    if (n >= N) return;
    int beg = off[n], end = off[n + 1];
    float p0 = 0, p1 = 0, q0 = 0, q1 = 0, r0 = 0, r1 = 0;
    for (int p = beg; p < end; p++) {
        int4 ed = edges[p];
        float a0 = __int_as_float(ed.y), a1 = __int_as_float(ed.z);
        float2 xv = ((const float2*)x)[ed.x];
        p0 = fmaf(a0, xv.x, p0);
        p1 = fmaf(a0, xv.y, p1);
        q0 = fmaf(a1, xv.x, q0);
        q1 = fmaf(a1, xv.y, q1);
        r0 += xv.x;
        r1 += xv.y;
    }
    float acc = bias[lane];
    acc = fmaf(p0, nnW[lane * 2], acc);
    acc = fmaf(p1, nnW[(32 + lane) * 2], acc);
    acc = fmaf(q0, nnW[lane * 2 + 1], acc);
    acc = fmaf(q1, nnW[(32 + lane) * 2 + 1], acc);
    acc = fmaf(r0, nnb[lane], acc);
    acc = fmaf(r1, nnb[32 + lane], acc);
    float2 xn = ((const float2*)x)[n];
    acc = fmaf(xn.x, root[lane], acc);
    acc = fmaf(xn.y, root[32 + lane], acc);
    hout[n * 32 + lane] = fmaxf(acc, 0.f);
}

__global__ __launch_bounds__(256) void conv32_kernel(
    const float* __restrict__ hin, const int* __restrict__ off,
    const int4* __restrict__ edges, const float* __restrict__ nnW,
    const float* __restrict__ nnb, const float* __restrict__ root,
    const float* __restrict__ bias, float* __restrict__ hout,
    const float* __restrict__ fc1W, const float* __restrict__ fc1b,
    const float* __restrict__ fc2W, const float* __restrict__ fc2b,
    float* __restrict__ out, int N) {
    __shared__ float lA0[1024], lA1[1024], lB[1024], lR[1024];
    __shared__ float ls[8 * 128];
    __shared__ float lsH[256];
    int tid = threadIdx.x;
    for (int k = tid; k < 1024; k += 256) {
        float2 w = ((const float2*)nnW)[k];
        lA0[k] = w.x;
        lA1[k] = w.y;
        lB[k] = nnb[k];
        lR[k] = root[k];
    }
    __syncthreads();
    int g = tid >> 5, lane = tid & 31;
    int n = blockIdx.x * 8 + g;
    float s0 = 0, s1 = 0, s2 = 0, s3 = 0;
    if (n < N) {
        int beg = off[n], end = off[n + 1];
        for (int p = beg; p < end; p++) {
            int4 ed = edges[p];
            float a0 = __int_as_float(ed.y), a1 = __int_as_float(ed.z);
            float xv = hin[ed.w + lane];
            s0 = fmaf(a0, xv, s0);
            s1 = fmaf(a1, xv, s1);
            s2 += xv;
        }
        s3 = hin[n * 32 + lane];
    }
    float* myls = &ls[g * 128];
    myls[lane] = s0;
    myls[32 + lane] = s1;
    myls[64 + lane] = s2;
    myls[96 + lane] = s3;
    __syncthreads();
    float acc = bias[lane];
#pragma unroll
    for (int i = 0; i < 32; i++) {
        acc = fmaf(myls[i], lA0[i * 32 + lane], acc);
        acc = fmaf(myls[32 + i], lA1[i * 32 + lane], acc);
        acc = fmaf(myls[64 + i], lB[i * 32 + lane], acc);
        acc = fmaf(myls[96 + i], lR[i * 32 + lane], acc);
    }
    acc = fmaxf(acc, 0.f);
    if (out == nullptr) {
        if (n < N) hout[n * 32 + lane] = acc;
    } else {
        lsH[g * 32 + lane] = acc;
        __syncthreads();
        float z = fc1b[lane];
#pragma unroll
        for (int o = 0; o < 32; o++) z = fmaf(lsH[g * 32 + o], fc1W[lane * 32 + o], z);
        z = fmaxf(z, 0.f);
        float v = z * fc2W[lane];
#pragma unroll
        for (int m = 1; m < 32; m <<= 1) v += __shfl_xor(v, m);
        if (lane == 0 && n < N) out[n] = v + fc2b[0];
    }
}

static inline size_t align256(size_t x) { return (x + 255) & ~(size_t)255; }

extern "C" void kernel_launch(void* const* d_in, const int* in_sizes, int n_in,
                              void* d_out, int out_size, void* d_ws, size_t ws_size,
                              hipStream_t stream) {
    const int N = in_sizes[0] / 2;   // 20000
    const int E = in_sizes[2] / 2;   // 150000
    const int NB = (N + 255) / 256;  // 79

    Params P;
    P.x = (const float*)d_in[0];
    const int* ei = (const int*)d_in[1];
    P.src = ei;
    P.dst = ei + E;
    P.ea = (const float*)d_in[2];
    P.nn1W = (const float*)d_in[3];
    P.nn1b = (const float*)d_in[4];
    P.root1 = (const float*)d_in[5];
    P.b1 = (const float*)d_in[6];
    P.nn2W = (const float*)d_in[7];
    P.nn2b = (const float*)d_in[8];
    P.root2 = (const float*)d_in[9];
    P.b2 = (const float*)d_in[10];
    P.nn3W = (const float*)d_in[11];
    P.nn3b = (const float*)d_in[12];
    P.root3 = (const float*)d_in[13];
    P.b3 = (const float*)d_in[14];
    P.fc1W = (const float*)d_in[15];
    P.fc1b = (const float*)d_in[16];
    P.fc2W = (const float*)d_in[17];
    P.fc2b = (const float*)d_in[18];

    char* w = (char*)d_ws;
    P.cnt = (int*)w;     w += align256((size_t)N * 4);
    P.agg = (int*)w;     w += align256((size_t)NB * 4);
    P.bars = (int*)w;    w += align256((size_t)NBARS * 9 * BAR_SLOT * 4);
    char* zero_end = w;  // zero everything from cnt to here (incl. padding)
    P.off = (int*)w;     w += align256((size_t)(N + 1) * 4);
    P.cur = (int*)w;     w += align256((size_t)N * 4);
    P.esc = (int*)w;     w += align256((size_t)N * 4);
    P.bsum = (int*)w;    w += align256((size_t)NB * 4);
    P.boff = (int*)w;    w += align256((size_t)NB * 4);
    P.edges = (int4*)w;  w += align256((size_t)E * 16);
    P.h1 = (float*)w;    w += align256((size_t)N * 32 * 4);
    P.h2 = (float*)w;    w += align256((size_t)N * 32 * 4);
    P.out = (float*)d_out;
    P.N = N;
    P.E = E;

    // Zero cnt + agg + bars in-kernel (hipMemsetAsync costs ~41us in-graph).
    int nzero = (int)((zero_end - (char*)P.cnt) / 4);
    zero_kernel<<<128, 256, 0, stream>>>(P.cnt, nzero);

    // Grid size: up to 4 blocks/CU, from the occupancy API; fallback 2/CU.
    int bpcu = 2, cus = 256;
    {
        int q = 0;
        if (hipOccupancyMaxActiveBlocksPerMultiprocessor(
                &q, (const void*)fused_kernel, 256, 0) == hipSuccess && q >= 1)
            bpcu = (q < 4) ? q : 4;
        int dev = 0, c = 0;
        if (hipGetDevice(&dev) == hipSuccess &&
            hipDeviceGetAttribute(&c, hipDeviceAttributeMultiprocessorCount, dev) ==
                hipSuccess && c > 0)
            cus = c;
    }
    int grid = bpcu * cus;

    void* args[] = {&P};
    hipError_t err = hipLaunchCooperativeKernel((const void*)fused_kernel, dim3(grid),
                                                dim3(256), args, 0, stream);
    if (err == hipSuccess) return;

    // Plan B: multi-kernel fallback (identical math; cnt already zeroed).
    int eb = (E + 255) / 256;
    hist_kernel<<<eb, 256, 0, stream>>>(P.dst, P.cnt, E);
    scanA_kernel<<<NB, 256, 0, stream>>>(P.cnt, P.esc, P.bsum, N);
    scanB_kernel<<<1, 128, 0, stream>>>(P.bsum, P.boff, P.off, NB, N);
    scanC_kernel<<<NB, 256, 0, stream>>>(P.esc, P.boff, P.off, P.cur, N);
    scatter_kernel<<<eb, 256, 0, stream>>>(P.src, P.dst, P.ea, P.cur, P.edges, E);
    int nbl = (N + 7) / 8;
    conv1_kernel<<<nbl, 256, 0, stream>>>(P.x, P.off, P.edges, P.nn1W, P.nn1b,
                                          P.root1, P.b1, P.h1, N);
    conv32_kernel<<<nbl, 256, 0, stream>>>(P.h1, P.off, P.edges, P.nn2W, P.nn2b,
                                           P.root2, P.b2, P.h2,
                                           nullptr, nullptr, nullptr, nullptr,
                                           nullptr, N);
    conv32_kernel<<<nbl, 256, 0, stream>>>(P.h2, P.off, P.edges, P.nn3W, P.nn3b,
                                           P.root3, P.b3, nullptr,
                                           P.fc1W, P.fc1b, P.fc2W, P.fc2b,
                                           (float*)d_out, N);
}

// Round 7
// 100.058 us; speedup vs baseline: 5.7021x; 3.3661x over previous
//
#include <hip/hip_runtime.h>

// NNConv x3 + MLP head. W_e = a0*A0 + a1*A1 + B (affine in 2 edge attrs) =>
// aggr_n = (sum a0*x_src)@A0 + (sum a1*x_src)@A1 + (sum x_src)@B.
// Multi-kernel pipeline (HSA dispatch boundaries ~3us are the cheap barrier;
// software grid barriers measured ~64us/sync on MI355X regardless of impl;
// in-graph hipMemsetAsync measured ~41us -> zero_kernel instead).
// Kernels: zero | hist | scanA | scanBC | scatter(int4 CSR) | conv1 | conv2 | conv3+head.

__global__ __launch_bounds__(256) void zero_kernel(int* p, int n) {
    int i = blockIdx.x * 256 + threadIdx.x;
    int gt = gridDim.x * 256;
    for (; i < n; i += gt) p[i] = 0;
}

__global__ void hist_kernel(const int* __restrict__ dst, int* __restrict__ cnt, int E) {
    int e = blockIdx.x * blockDim.x + threadIdx.x;
    if (e < E) atomicAdd(&cnt[dst[e]], 1);
}

// scanA: per-chunk (256 elems) LDS scan -> esc (exclusive within chunk), bsum.
__global__ __launch_bounds__(256) void scanA_kernel(const int* __restrict__ cnt,
                                                    int* __restrict__ esc,
                                                    int* __restrict__ bsum, int N) {
    __shared__ int sh[256];
    int t = threadIdx.x;
    int i = blockIdx.x * 256 + t;
    int v = (i < N) ? cnt[i] : 0;
    sh[t] = v;
    __syncthreads();
    for (int d = 1; d < 256; d <<= 1) {
        int u = (t >= d) ? sh[t - d] : 0;
        __syncthreads();
        sh[t] += u;
        __syncthreads();
    }
    if (i < N) esc[i] = sh[t] - v;
    if (t == 255) bsum[blockIdx.x] = sh[255];
}

// scanBC: every block redundantly scans the NB chunk sums in LDS (NB=79 <= 128),
// then writes off/cur for its own chunk. Merges old scanB+scanC (one dispatch).
__global__ __launch_bounds__(256) void scanBC_kernel(const int* __restrict__ esc,
                                                     const int* __restrict__ bsum,
                                                     int* __restrict__ off,
                                                     int* __restrict__ cur,
                                                     int NB, int N) {
    __shared__ int sh[128];
    int t = threadIdx.x;
    if (t < 128) {
        int v = (t < NB) ? bsum[t] : 0;
        sh[t] = v;
    }
    __syncthreads();
    for (int d = 1; d < 128; d <<= 1) {
        int u = 0;
        if (t < 128 && t >= d) u = sh[t - d];
        __syncthreads();
        if (t < 128) sh[t] += u;
        __syncthreads();
    }
    // sh[k] = inclusive sum of bsum[0..k]; exclusive offset of chunk b = sh[b-1]
    int b = blockIdx.x;
    int boff = (b == 0) ? 0 : sh[b - 1];
    int i = b * 256 + t;
    if (i < N) {
        int o = boff + esc[i];
        off[i] = o;
        cur[i] = o;
    }
    if (b == 0 && t == 0) off[N] = sh[NB - 1];
}

__global__ void scatter_kernel(const int* __restrict__ src, const int* __restrict__ dst,
                               const float* __restrict__ ea, int* __restrict__ cur,
                               int4* __restrict__ edges, int E) {
    int e = blockIdx.x * blockDim.x + threadIdx.x;
    if (e < E) {
        int d = dst[e];
        int p = atomicAdd(&cur[d], 1);
        float2 a = ((const float2*)ea)[e];
        int s = src[e];
        int4 ed;
        ed.x = s;
        ed.y = __float_as_int(a.x);
        ed.z = __float_as_int(a.y);
        ed.w = s * 32;
        edges[p] = ed;
    }
}

// conv1: in=2, out=32. 8 nodes/block, 32 lanes/node (lane = out feature).
__global__ __launch_bounds__(256) void conv1_kernel(
    const float* __restrict__ x, const int* __restrict__ off,
    const int4* __restrict__ edges, const float* __restrict__ nnW,
    const float* __restrict__ nnb, const float* __restrict__ root,
    const float* __restrict__ bias, float* __restrict__ hout, int N) {
    int tid = threadIdx.x;
    int g = tid >> 5, lane = tid & 31;
    int n = blockIdx.x * 8 + g;
    if (n >= N) return;
    int beg = off[n], end = off[n + 1];
    float p0 = 0, p1 = 0, q0 = 0, q1 = 0, r0 = 0, r1 = 0;
    for (int p = beg; p < end; p++) {
        int4 ed = edges[p];
        float a0 = __int_as_float(ed.y), a1 = __int_as_float(ed.z);
        float2 xv = ((const float2*)x)[ed.x];
        p0 = fmaf(a0, xv.x, p0);
        p1 = fmaf(a0, xv.y, p1);
        q0 = fmaf(a1, xv.x, q0);
        q1 = fmaf(a1, xv.y, q1);
        r0 += xv.x;
        r1 += xv.y;
    }
    float acc = bias[lane];
    acc = fmaf(p0, nnW[lane * 2], acc);
    acc = fmaf(p1, nnW[(32 + lane) * 2], acc);
    acc = fmaf(q0, nnW[lane * 2 + 1], acc);
    acc = fmaf(q1, nnW[(32 + lane) * 2 + 1], acc);
    acc = fmaf(r0, nnb[lane], acc);
    acc = fmaf(r1, nnb[32 + lane], acc);
    float2 xn = ((const float2*)x)[n];
    acc = fmaf(xn.x, root[lane], acc);
    acc = fmaf(xn.y, root[32 + lane], acc);
    hout[n * 32 + lane] = fmaxf(acc, 0.f);
}

// conv2/conv3: in=out=32. 8 nodes/block, 32 lanes/node. Weights staged in LDS.
// If out != null: fuse fc1(relu)+fc2 head, write out[N] instead of hout.
__global__ __launch_bounds__(256) void conv32_kernel(
    const float* __restrict__ hin, const int* __restrict__ off,
    const int4* __restrict__ edges, const float* __restrict__ nnW,
    const float* __restrict__ nnb, const float* __restrict__ root,
    const float* __restrict__ bias, float* __restrict__ hout,
    const float* __restrict__ fc1W, const float* __restrict__ fc1b,
    const float* __restrict__ fc2W, const float* __restrict__ fc2b,
    float* __restrict__ out, int N) {
    __shared__ float lA0[1024], lA1[1024], lB[1024], lR[1024];
    __shared__ float ls[8 * 128];
    __shared__ float lsH[256];
    int tid = threadIdx.x;
    for (int k = tid; k < 1024; k += 256) {
        float2 w = ((const float2*)nnW)[k];
        lA0[k] = w.x;
        lA1[k] = w.y;
        lB[k] = nnb[k];
        lR[k] = root[k];
    }
    __syncthreads();
    int g = tid >> 5, lane = tid & 31;
    int n = blockIdx.x * 8 + g;
    float s0 = 0, s1 = 0, s2 = 0, s3 = 0;
    if (n < N) {
        int beg = off[n], end = off[n + 1];
        for (int p = beg; p < end; p++) {
            int4 ed = edges[p];
            float a0 = __int_as_float(ed.y), a1 = __int_as_float(ed.z);
            float xv = hin[ed.w + lane];
            s0 = fmaf(a0, xv, s0);
            s1 = fmaf(a1, xv, s1);
            s2 += xv;
        }
        s3 = hin[n * 32 + lane];
    }
    float* myls = &ls[g * 128];
    myls[lane] = s0;
    myls[32 + lane] = s1;
    myls[64 + lane] = s2;
    myls[96 + lane] = s3;
    __syncthreads();
    float acc = bias[lane];
#pragma unroll
    for (int i = 0; i < 32; i++) {
        acc = fmaf(myls[i], lA0[i * 32 + lane], acc);
        acc = fmaf(myls[32 + i], lA1[i * 32 + lane], acc);
        acc = fmaf(myls[64 + i], lB[i * 32 + lane], acc);
        acc = fmaf(myls[96 + i], lR[i * 32 + lane], acc);
    }
    acc = fmaxf(acc, 0.f);
    if (out == nullptr) {
        if (n < N) hout[n * 32 + lane] = acc;
    } else {
        lsH[g * 32 + lane] = acc;
        __syncthreads();
        float z = fc1b[lane];
#pragma unroll
        for (int o = 0; o < 32; o++) z = fmaf(lsH[g * 32 + o], fc1W[lane * 32 + o], z);
        z = fmaxf(z, 0.f);
        float v = z * fc2W[lane];
#pragma unroll
        for (int m = 1; m < 32; m <<= 1) v += __shfl_xor(v, m);
        if (lane == 0 && n < N) out[n] = v + fc2b[0];
    }
}

static inline size_t align256(size_t x) { return (x + 255) & ~(size_t)255; }

extern "C" void kernel_launch(void* const* d_in, const int* in_sizes, int n_in,
                              void* d_out, int out_size, void* d_ws, size_t ws_size,
                              hipStream_t stream) {
    const float* x = (const float*)d_in[0];
    const int* ei = (const int*)d_in[1];
    const float* ea = (const float*)d_in[2];
    const float* nn1W = (const float*)d_in[3];
    const float* nn1b = (const float*)d_in[4];
    const float* root1 = (const float*)d_in[5];
    const float* b1 = (const float*)d_in[6];
    const float* nn2W = (const float*)d_in[7];
    const float* nn2b = (const float*)d_in[8];
    const float* root2 = (const float*)d_in[9];
    const float* b2 = (const float*)d_in[10];
    const float* nn3W = (const float*)d_in[11];
    const float* nn3b = (const float*)d_in[12];
    const float* root3 = (const float*)d_in[13];
    const float* b3 = (const float*)d_in[14];
    const float* fc1W = (const float*)d_in[15];
    const float* fc1b = (const float*)d_in[16];
    const float* fc2W = (const float*)d_in[17];
    const float* fc2b = (const float*)d_in[18];

    const int N = in_sizes[0] / 2;   // 20000
    const int E = in_sizes[2] / 2;   // 150000
    const int* src = ei;
    const int* dst = ei + E;
    const int NB = (N + 255) / 256;  // 79

    char* w = (char*)d_ws;
    int* cnt = (int*)w;     w += align256((size_t)N * 4);
    int* off = (int*)w;     w += align256((size_t)(N + 1) * 4);
    int* cur = (int*)w;     w += align256((size_t)N * 4);
    int* esc = (int*)w;     w += align256((size_t)N * 4);
    int* bsum = (int*)w;    w += align256((size_t)NB * 4);
    int4* edges = (int4*)w; w += align256((size_t)E * 16);
    float* h1 = (float*)w;  w += align256((size_t)N * 32 * 4);
    float* h2 = (float*)w;  w += align256((size_t)N * 32 * 4);

    float* out = (float*)d_out;

    zero_kernel<<<128, 256, 0, stream>>>(cnt, N);

    int eb = (E + 255) / 256;
    hist_kernel<<<eb, 256, 0, stream>>>(dst, cnt, E);
    scanA_kernel<<<NB, 256, 0, stream>>>(cnt, esc, bsum, N);
    scanBC_kernel<<<NB, 256, 0, stream>>>(esc, bsum, off, cur, NB, N);
    scatter_kernel<<<eb, 256, 0, stream>>>(src, dst, ea, cur, edges, E);

    int nb = (N + 7) / 8;
    conv1_kernel<<<nb, 256, 0, stream>>>(x, off, edges, nn1W, nn1b, root1, b1, h1, N);
    conv32_kernel<<<nb, 256, 0, stream>>>(h1, off, edges, nn2W, nn2b, root2, b2, h2,
                                          nullptr, nullptr, nullptr, nullptr,
                                          nullptr, N);
    conv32_kernel<<<nb, 256, 0, stream>>>(h2, off, edges, nn3W, nn3b, root3, b3,
                                          nullptr, fc1W, fc1b, fc2W, fc2b, out, N);
}